// Round 6
// baseline (948.486 us; speedup 1.0000x reference)
//
#include <hip/hip_runtime.h>
#include <cstdint>

#define T_LEN 1000
#define NB    256

__device__ __forceinline__ float rcpf_(float x)     { return __builtin_amdgcn_rcpf(x); }
__device__ __forceinline__ float sigmoidf_(float x) { return rcpf_(1.f + __expf(-x)); }
__device__ __forceinline__ float tanhf_(float x) {
    float e = __expf(2.f * x);
    return 1.f - 2.f * rcpf_(e + 1.f);
}
__device__ __forceinline__ float softplusf_(float x) {
    return fmaxf(x, 0.f) + __logf(1.f + __expf(-fabsf(x)));
}
__device__ __forceinline__ float bcast_(float v, int l) {
    return __uint_as_float(__builtin_amdgcn_readlane(__float_as_uint(v), l));
}

// Raw barrier WITHOUT vmcnt drain: orders LDS (lgkmcnt(0)) + rendezvous; global loads
// (the DMA wave's ring fills) stay in flight across it.
#define BARRIER_SYNC() asm volatile("s_waitcnt lgkmcnt(0)\n\ts_barrier" ::: "memory")

// async global->LDS, 4 bytes/lane; global addr per-lane, LDS dest = base + lane*4
__device__ __forceinline__ void gload_lds(const float* g, float* l) {
    __builtin_amdgcn_global_load_lds(
        (const __attribute__((address_space(1))) uint32_t*)g,
        (__attribute__((address_space(3))) uint32_t*)l,
        4, 0, 0);
}

// ---------------- K1: gi2 = mini_batch @ W_ih2^T + b_ih2  -> out[b,t,0:30] (scratch) --------
__global__ __launch_bounds__(256) void gi2_kernel(
    const float* __restrict__ x, const float* __restrict__ W,
    const float* __restrict__ bias, float* __restrict__ out)
{
    __shared__ float xsT[100 * 67];          // xsT[k*67 + r], 26.8 KB

    const int tid = threadIdx.x;
    const int64_t base = (int64_t)blockIdx.x * (64 * 100);
    const float4* gx = (const float4*)(x + base);

#pragma unroll
    for (int it = 0; it < 7; ++it) {
        int i = tid + it * 256;
        if (i < 1600) {
            int r  = i / 25;
            int k4 = i - r * 25;
            float4 v = gx[i];                 // coalesced 16B/lane
            xsT[(4 * k4 + 0) * 67 + r] = v.x;
            xsT[(4 * k4 + 1) * 67 + r] = v.y;
            xsT[(4 * k4 + 2) * 67 + r] = v.z;
            xsT[(4 * k4 + 3) * 67 + r] = v.w;
        }
    }
    __syncthreads();

    const int lane = tid & 63;                               // row within tile
    const int wv   = __builtin_amdgcn_readfirstlane(tid >> 6);
    const int j0   = wv * 8;                                 // 8 output cols per wave

    float acc[8];
#pragma unroll
    for (int jj = 0; jj < 8; ++jj) acc[jj] = 0.f;

    for (int k = 0; k < 100; ++k) {
        float xv = xsT[k * 67 + lane];
#pragma unroll
        for (int jj = 0; jj < 8; ++jj) {
            int j = j0 + jj; j = j > 29 ? 29 : j;            // wave-uniform -> s_load
            acc[jj] = fmaf(xv, W[j * 100 + k], acc[jj]);
        }
    }
    float* orow = out + base + (int64_t)lane * 100;
#pragma unroll
    for (int jj = 0; jj < 8; ++jj) {
        int j = j0 + jj;
        if (j < 30) orow[j] = acc[jj] + bias[j];
    }
}

// ---------------- K2: sequential scan. 1 block / batch element, 3 waves ---------------------
// wave0: h1 critical chain.  wave1: h2 GRU + emitter (lagged 1 step) + stores.
// wave2: DMA — fills a 4-slot LDS ring with {eps(t), gi2(t)} via global_load_lds,
//         counted vmcnt(6) (never 0) before each barrier. HBM latency fully off-loop.
__global__ __launch_bounds__(192) void scan_kernel(
    const float* __restrict__ eps,
    const float* __restrict__ W_ih1, const float* __restrict__ W_hh1,
    const float* __restrict__ b_ih1, const float* __restrict__ b_hh1,
    const float* __restrict__ W_hh2, const float* __restrict__ b_hh2,
    const float* __restrict__ h1_0,  const float* __restrict__ h2_0,
    const float* __restrict__ Wt1,   const float* __restrict__ bt1,
    const float* __restrict__ Wloc,  const float* __restrict__ bloc,
    const float* __restrict__ Wsc,   const float* __restrict__ bsc,
    const float* __restrict__ We1,   const float* __restrict__ be1,
    const float* __restrict__ We2,   const float* __restrict__ be2,
    const float* __restrict__ We3,   const float* __restrict__ be3,
    float* out)
{
    __shared__ __align__(16) float ring[4][192];     // slot: [0..127]=eps(t), [128..191]=gi2(t)
    __shared__ __align__(16) float ss2[2][52];       // z-tilde halves (pads zeroed), wave0-private
    __shared__ __align__(16) float sh1ring[2][12];   // h1 after step t -> slot t&1 (w0 -> w1)

    const int lane = threadIdx.x & 63;
    const int64_t rowbase = (int64_t)blockIdx.x * T_LEN * 100;
    const int wave = __builtin_amdgcn_readfirstlane((int)(threadIdx.x >> 6));

    if (wave == 0) {
        // ================= wave0: h1 chain =================
        const int j  = lane & 31;
        const int jc = j < 30 ? j : 29;        // clamped row (garbage lanes unused)
        const int h  = lane >> 5;              // k-half for the 100-deep gi1 reduction
        const int lt = lane < 20 ? lane : 19;
        const int ls = lane < 50 ? lane : 49;

        float wt1r[10], whh1r[10], wscA[20], wscB[20], wbig[52], Cr[20];
#pragma unroll
        for (int k = 0; k < 10; ++k) {
            wt1r[k]  = Wt1[lt * 10 + k];
            whh1r[k] = W_hh1[jc * 10 + k];
        }
        float bt1r  = bt1[lt];
        float bhh1r = b_hh1[jc];
        float br1   = b_ih1[jc];
#pragma unroll
        for (int l = 0; l < 20; ++l) {
            wscA[l] = Wsc[ls * 20 + l];
            wscB[l] = Wsc[(ls + 50) * 20 + l];
        }
        float bscA = bsc[ls], bscB = bsc[ls + 50];
#pragma unroll
        for (int i = 0; i < 50; ++i) wbig[i] = W_ih1[jc * 100 + h * 50 + i];
        wbig[50] = 0.f; wbig[51] = 0.f;

        // one-off fold: Cr[l] = (W_ih1 @ Wloc)[jc][l],  dr = (W_ih1 @ bloc)[jc]
        float dr = 0.f;
#pragma unroll
        for (int l = 0; l < 20; ++l) Cr[l] = 0.f;
        for (int kk = 0; kk < 100; ++kk) {
            float w = W_ih1[jc * 100 + kk];
            dr = fmaf(w, bloc[kk], dr);
#pragma unroll
            for (int l = 0; l < 20; ++l) Cr[l] = fmaf(w, Wloc[kk * 20 + l], Cr[l]);
        }

        if (lane < 2) { ss2[0][50 + lane] = 0.f; ss2[1][50 + lane] = 0.f; }

        float h1keep = h1_0[lane < 10 ? lane : 0];   // per-lane own h1[j] (lanes 0..9)
        float sh1_[10];
#pragma unroll
        for (int k = 0; k < 10; ++k) sh1_[k] = h1_0[k];   // uniform -> SGPRs

        BARRIER_SYNC();                                    // match DMA prologue barrier

#pragma unroll 1
        for (int t = 0; t <= T_LEN; ++t) {
            if (t < T_LEN) {
                const int slot = t & 3;
                // eps(t) from LDS ring (filled >=1 step ago): issue early, use ~150cy later
                float eA = ring[slot][ls];
                float eB = ring[slot][ls + 50];

                // hid + gh1 from SGPR-resident h1 (2 accumulators each)
                float ha = bt1r, hb = 0.f, ga = bhh1r, gb = 0.f;
#pragma unroll
                for (int k = 0; k < 5; ++k) {
                    ha = fmaf(wt1r[2 * k],      sh1_[2 * k],     ha);
                    hb = fmaf(wt1r[2 * k + 1],  sh1_[2 * k + 1], hb);
                    ga = fmaf(whh1r[2 * k],     sh1_[2 * k],     ga);
                    gb = fmaf(whh1r[2 * k + 1], sh1_[2 * k + 1], gb);
                }
                float hidv = fmaxf(ha + hb, 0.f);
                float gh1v = ga + gb;

                float sgh[20];
#pragma unroll
                for (int l = 0; l < 20; ++l) sgh[l] = bcast_(hidv, l);

                // sc pair + folded loc term gq (2 accumulators per chain)
                float sA0 = bscA, sA1 = 0.f, sB0 = bscB, sB1 = 0.f, q0 = dr, q1 = 0.f;
#pragma unroll
                for (int l = 0; l < 10; ++l) {
                    sA0 = fmaf(wscA[2 * l],     sgh[2 * l],     sA0);
                    sA1 = fmaf(wscA[2 * l + 1], sgh[2 * l + 1], sA1);
                    sB0 = fmaf(wscB[2 * l],     sgh[2 * l],     sB0);
                    sB1 = fmaf(wscB[2 * l + 1], sgh[2 * l + 1], sB1);
                    q0  = fmaf(Cr[2 * l],       sgh[2 * l],     q0);
                    q1  = fmaf(Cr[2 * l + 1],   sgh[2 * l + 1], q1);
                }
                float gq = q0 + q1;
                float zA = softplusf_(sA0 + sA1) * eA;
                float zB = softplusf_(sB0 + sB1) * eB;
                if (lane < 50) { ss2[0][lane] = zA; ss2[1][lane] = zB; }

                __builtin_amdgcn_wave_barrier();

                // gi1 partial: 50-deep dot over own k-half, 4 accumulators
                const float4* sp4 = (const float4*)(&ss2[h][0]);
                float p0 = 0.f, p1 = 0.f, p2 = 0.f, p3 = 0.f;
#pragma unroll
                for (int c = 0; c < 13; ++c) {
                    float4 v = sp4[c];
                    p0 = fmaf(wbig[4 * c + 0], v.x, p0);
                    p1 = fmaf(wbig[4 * c + 1], v.y, p1);
                    p2 = fmaf(wbig[4 * c + 2], v.z, p2);
                    p3 = fmaf(wbig[4 * c + 3], v.w, p3);
                }
                float p = (p0 + p1) + (p2 + p3);
                float gi1v = p + __shfl_xor(p, 32) + br1 + gq;
                float av   = gi1v + gh1v;
                float a10  = __shfl(av,   lane + 10);
                float gin  = __shfl(gi1v, lane + 20);
                float ghn  = __shfl(gh1v, lane + 20);
                if (lane < 10) {
                    float r = sigmoidf_(av);
                    float u = sigmoidf_(a10);
                    float n = tanhf_(fmaf(r, ghn, gin));
                    h1keep = fmaf(u, h1keep - n, n);       // (1-u)*n + u*h1
                    sh1ring[t & 1][lane] = h1keep;          // hand-off to wave1
                }
#pragma unroll
                for (int k = 0; k < 10; ++k) sh1_[k] = bcast_(h1keep, k);
            }
            BARRIER_SYNC();
        }
    } else if (wave == 1) {
        // ================= wave1: h2 chain (SGPR state) + emitter(t-1) =================
        const int lt20 = lane < 20 ? lane : 19;
        const int l30  = lane < 30 ? lane : 29;
        const int ls   = lane < 50 ? lane : 49;

        float whh2r[10];
#pragma unroll
        for (int k = 0; k < 10; ++k) whh2r[k] = W_hh2[l30 * 10 + k];
        float bhh2r = b_hh2[l30];

        float we1r[20], we2r[20], we3A[20], we3B[20];
#pragma unroll
        for (int k = 0; k < 20; ++k) {
            we1r[k] = We1[lt20 * 20 + k];
            we2r[k] = We2[lt20 * 20 + k];
            we3A[k] = We3[ls * 20 + k];
            we3B[k] = We3[(ls + 50) * 20 + k];
        }
        float be1r = be1[lt20], be2r = be2[lt20];
        float be3A = be3[ls],   be3B = be3[ls + 50];

        float h2keep = h2_0[lane < 10 ? lane : 0];
        float g2c[10], g2p[10];                  // H2(t), H2(t-1) as broadcast scalars
#pragma unroll
        for (int k = 0; k < 10; ++k) { g2c[k] = h2_0[k]; g2p[k] = h2_0[k]; }

        BARRIER_SYNC();                                    // match DMA prologue barrier

#pragma unroll 1
        for (int t = 0; t <= T_LEN; ++t) {
            const bool upd = (t < T_LEN);
            // gi2(t) from LDS ring: issue early, use ~100cy later
            float gi2v = 0.f;
            if (upd) gi2v = ring[t & 3][128 + l30];

            // early h1(t-1) read for emitter (latency hidden under h2 GRU)
            float4 d0 = make_float4(0.f, 0.f, 0.f, 0.f);
            float4 d1 = d0; float d8 = 0.f, d9 = 0.f;
            if (t >= 1) {
                const int s1 = (t - 1) & 1;
                d0 = *(const float4*)(&sh1ring[s1][0]);
                d1 = *(const float4*)(&sh1ring[s1][4]);
                d8 = sh1ring[s1][8]; d9 = sh1ring[s1][9];
            }

            if (upd) {
                float ga = bhh2r, gb = 0.f;
#pragma unroll
                for (int k = 0; k < 5; ++k) {
                    ga = fmaf(whh2r[2 * k],     g2c[2 * k],     ga);
                    gb = fmaf(whh2r[2 * k + 1], g2c[2 * k + 1], gb);
                }
                float gh2v = ga + gb;
                float a2  = gi2v + gh2v;
                float a10 = __shfl(a2,   lane + 10);
                float gin = __shfl(gi2v, lane + 20);
                float ghn = __shfl(gh2v, lane + 20);
                if (lane < 10) {
                    float r = sigmoidf_(a2);
                    float u = sigmoidf_(a10);
                    float n = tanhf_(fmaf(r, ghn, gin));
                    h2keep = fmaf(u, h2keep - n, n);       // H2(t+1)
                }
            }

            if (t >= 1) {
                // emitter step s = t-1: h1(s) from LDS, H2(s)=g2p broadcast
                float ea = be1r, eb = 0.f;
                ea = fmaf(we1r[0], d0.x, ea); eb = fmaf(we1r[1], d0.y, eb);
                ea = fmaf(we1r[2], d0.z, ea); eb = fmaf(we1r[3], d0.w, eb);
                ea = fmaf(we1r[4], d1.x, ea); eb = fmaf(we1r[5], d1.y, eb);
                ea = fmaf(we1r[6], d1.z, ea); eb = fmaf(we1r[7], d1.w, eb);
                ea = fmaf(we1r[8], d8,   ea); eb = fmaf(we1r[9], d9,   eb);
#pragma unroll
                for (int k = 0; k < 5; ++k) {
                    ea = fmaf(we1r[10 + 2 * k],     g2p[2 * k],     ea);
                    eb = fmaf(we1r[10 + 2 * k + 1], g2p[2 * k + 1], eb);
                }
                float e1v = fmaxf(ea + eb, 0.f);

                float se1v[20];
#pragma unroll
                for (int l = 0; l < 20; ++l) se1v[l] = bcast_(e1v, l);

                float fa = be2r, fb = 0.f;
#pragma unroll
                for (int k = 0; k < 10; ++k) {
                    fa = fmaf(we2r[2 * k],     se1v[2 * k],     fa);
                    fb = fmaf(we2r[2 * k + 1], se1v[2 * k + 1], fb);
                }
                float e2v = fmaxf(fa + fb, 0.f);

                float se2v[20];
#pragma unroll
                for (int l = 0; l < 20; ++l) se2v[l] = bcast_(e2v, l);

                float xa0 = be3A, xa1 = 0.f, xb0 = be3B, xb1 = 0.f;
#pragma unroll
                for (int l = 0; l < 10; ++l) {
                    xa0 = fmaf(we3A[2 * l],     se2v[2 * l],     xa0);
                    xa1 = fmaf(we3A[2 * l + 1], se2v[2 * l + 1], xa1);
                    xb0 = fmaf(we3B[2 * l],     se2v[2 * l],     xb0);
                    xb1 = fmaf(we3B[2 * l + 1], se2v[2 * l + 1], xb1);
                }
                float xA = sigmoidf_(xa0 + xa1);
                float xB = sigmoidf_(xb0 + xb1);
                if (lane < 50) {
                    int64_t ro = rowbase + (int64_t)(t - 1) * 100;
                    out[ro + lane]      = xA;               // fire-and-forget stores
                    out[ro + lane + 50] = xB;
                }
            }

            if (upd) {
#pragma unroll
                for (int k = 0; k < 10; ++k) g2p[k] = g2c[k];
#pragma unroll
                for (int k = 0; k < 10; ++k) g2c[k] = bcast_(h2keep, k);
            }
            BARRIER_SYNC();
        }
    } else {
        // ================= wave2: DMA ring fill =================
        const float* erow = eps + rowbase;
        const float* grow = out + rowbase;                 // gi2 scratch (written by K1)
        const int le2 = 64 + (lane < 36 ? lane : 35);      // eps upper part, clamped
        const int lg  = lane < 30 ? lane : 29;             // gi2, clamped

        // prologue: fill slots 0,1,2
#pragma unroll
        for (int t0 = 0; t0 < 3; ++t0) {
            const float* ep = erow + (int64_t)t0 * 100;
            const float* gp = grow + (int64_t)t0 * 100;
            gload_lds(ep + lane, &ring[t0][0]);
            gload_lds(ep + le2,  &ring[t0][64]);
            gload_lds(gp + lg,   &ring[t0][128]);
        }
        asm volatile("s_waitcnt vmcnt(6)" ::: "memory");   // slot 0 complete
        BARRIER_SYNC();

#pragma unroll 1
        for (int t = 0; t <= T_LEN; ++t) {
            const int tp   = (t + 3 < T_LEN) ? t + 3 : T_LEN - 1;   // clamped (tail unused)
            const int slot = (t + 3) & 3;
            const float* ep = erow + (int64_t)tp * 100;
            const float* gp = grow + (int64_t)tp * 100;
            gload_lds(ep + lane, &ring[slot][0]);
            gload_lds(ep + le2,  &ring[slot][64]);
            gload_lds(gp + lg,   &ring[slot][128]);
            asm volatile("s_waitcnt vmcnt(6)" ::: "memory");        // slot t+1 complete
            BARRIER_SYNC();
        }
    }
}

extern "C" void kernel_launch(void* const* d_in, const int* in_sizes, int n_in,
                              void* d_out, int out_size, void* d_ws, size_t ws_size,
                              hipStream_t stream) {
    const float* mini_batch = (const float*)d_in[0];
    const float* eps        = (const float*)d_in[1];
    const float* W_ih1      = (const float*)d_in[2];
    const float* W_hh1      = (const float*)d_in[3];
    const float* b_ih1      = (const float*)d_in[4];
    const float* b_hh1      = (const float*)d_in[5];
    const float* W_ih2      = (const float*)d_in[6];
    const float* W_hh2      = (const float*)d_in[7];
    const float* b_ih2      = (const float*)d_in[8];
    const float* b_hh2      = (const float*)d_in[9];
    const float* h1_0       = (const float*)d_in[10];
    const float* h2_0       = (const float*)d_in[11];
    const float* Wt1        = (const float*)d_in[12];
    const float* bt1        = (const float*)d_in[13];
    const float* Wloc       = (const float*)d_in[14];
    const float* bloc       = (const float*)d_in[15];
    const float* Wsc        = (const float*)d_in[16];
    const float* bsc        = (const float*)d_in[17];
    const float* We1        = (const float*)d_in[18];
    const float* be1        = (const float*)d_in[19];
    const float* We2        = (const float*)d_in[20];
    const float* be2        = (const float*)d_in[21];
    const float* We3        = (const float*)d_in[22];
    const float* be3        = (const float*)d_in[23];
    float* out = (float*)d_out;

    // K1: gi2 precompute into out[.., 0:30] (scratch region, overwritten later by K2)
    gi2_kernel<<<(NB * T_LEN) / 64, 256, 0, stream>>>(mini_batch, W_ih2, b_ih2, out);

    // K2: sequential scan, one block per batch element, 2 compute waves + 1 DMA wave
    scan_kernel<<<NB, 192, 0, stream>>>(eps, W_ih1, W_hh1, b_ih1, b_hh1, W_hh2, b_hh2,
                                        h1_0, h2_0, Wt1, bt1, Wloc, bloc, Wsc, bsc,
                                        We1, be1, We2, be2, We3, be3, out);
}

// Round 7
// 832.784 us; speedup vs baseline: 1.1389x; 1.1389x over previous
//
#include <hip/hip_runtime.h>
#include <cstdint>

#define T_LEN 1000
#define NB    256

__device__ __forceinline__ float rcpf_(float x)     { return __builtin_amdgcn_rcpf(x); }
__device__ __forceinline__ float sigmoidf_(float x) { return rcpf_(1.f + __expf(-x)); }
__device__ __forceinline__ float tanhf_(float x) {
    float e = __expf(2.f * x);
    return 1.f - 2.f * rcpf_(e + 1.f);
}
__device__ __forceinline__ float softplusf_(float x) {
    return fmaxf(x, 0.f) + __logf(1.f + __expf(-fabsf(x)));
}
__device__ __forceinline__ float bcast_(float v, int l) {
    return __uint_as_float(__builtin_amdgcn_readlane(__float_as_uint(v), l));
}

// ---------------- K1: gi2 = mini_batch @ W_ih2^T + b_ih2  -> out[b,t,0:30] (scratch) --------
__global__ __launch_bounds__(256) void gi2_kernel(
    const float* __restrict__ x, const float* __restrict__ W,
    const float* __restrict__ bias, float* __restrict__ out)
{
    __shared__ float xsT[100 * 67];          // xsT[k*67 + r], 26.8 KB

    const int tid = threadIdx.x;
    const int64_t base = (int64_t)blockIdx.x * (64 * 100);
    const float4* gx = (const float4*)(x + base);

#pragma unroll
    for (int it = 0; it < 7; ++it) {
        int i = tid + it * 256;
        if (i < 1600) {
            int r  = i / 25;
            int k4 = i - r * 25;
            float4 v = gx[i];                 // coalesced 16B/lane
            xsT[(4 * k4 + 0) * 67 + r] = v.x;
            xsT[(4 * k4 + 1) * 67 + r] = v.y;
            xsT[(4 * k4 + 2) * 67 + r] = v.z;
            xsT[(4 * k4 + 3) * 67 + r] = v.w;
        }
    }
    __syncthreads();

    const int lane = tid & 63;                               // row within tile
    const int wv   = __builtin_amdgcn_readfirstlane(tid >> 6);
    const int j0   = wv * 8;                                 // 8 output cols per wave

    float acc[8];
#pragma unroll
    for (int jj = 0; jj < 8; ++jj) acc[jj] = 0.f;

    for (int k = 0; k < 100; ++k) {
        float xv = xsT[k * 67 + lane];
#pragma unroll
        for (int jj = 0; jj < 8; ++jj) {
            int j = j0 + jj; j = j > 29 ? 29 : j;            // wave-uniform -> s_load
            acc[jj] = fmaf(xv, W[j * 100 + k], acc[jj]);
        }
    }
    float* orow = out + base + (int64_t)lane * 100;
#pragma unroll
    for (int jj = 0; jj < 8; ++jj) {
        int j = j0 + jj;
        if (j < 30) orow[j] = acc[jj] + bias[j];
    }
}

// ---------------- K2: sequential scans. 1 block / batch element, 2 FREE-RUNNING waves -------
// wave0: h1 chain only -> h1[t] to out[b,t,30:40].
// wave1: h2 chain only (gi2 from out[b,t,0:30]) -> PRE-update h2 (=h2_shift[t]) to
//        out[b,t,40:50].  The two waves never communicate: ZERO barriers, no shared LDS.
// eps/gi2 prefetch distance 2 via unroll-2 use-then-overwrite registers (no rotation movs).

#define H1_STEP(T, EA, EB, P)                                            \
    do {                                                                 \
        float ha = bt1r, hb = 0.f, ga = bhh1r, gb = 0.f;                 \
        _Pragma("unroll")                                                \
        for (int k_ = 0; k_ < 5; ++k_) {                                 \
            ha = fmaf(wt1r[2*k_],    sh1_[2*k_],   ha);                  \
            hb = fmaf(wt1r[2*k_+1],  sh1_[2*k_+1], hb);                  \
            ga = fmaf(whh1r[2*k_],   sh1_[2*k_],   ga);                  \
            gb = fmaf(whh1r[2*k_+1], sh1_[2*k_+1], gb);                  \
        }                                                                \
        float hidv = fmaxf(ha + hb, 0.f);                                \
        float gh1v = ga + gb;                                            \
        float sgh[20];                                                   \
        _Pragma("unroll")                                                \
        for (int l_ = 0; l_ < 20; ++l_) sgh[l_] = bcast_(hidv, l_);      \
        float sA0 = bscA, sA1 = 0.f, sB0 = bscB, sB1 = 0.f;              \
        float q0 = dr, q1 = 0.f;                                         \
        _Pragma("unroll")                                                \
        for (int l_ = 0; l_ < 10; ++l_) {                                \
            sA0 = fmaf(wscA[2*l_],   sgh[2*l_],   sA0);                  \
            sA1 = fmaf(wscA[2*l_+1], sgh[2*l_+1], sA1);                  \
            sB0 = fmaf(wscB[2*l_],   sgh[2*l_],   sB0);                  \
            sB1 = fmaf(wscB[2*l_+1], sgh[2*l_+1], sB1);                  \
            q0  = fmaf(Cr[2*l_],     sgh[2*l_],   q0);                   \
            q1  = fmaf(Cr[2*l_+1],   sgh[2*l_+1], q1);                   \
        }                                                                \
        float gq = q0 + q1;                                              \
        float zA = softplusf_(sA0 + sA1) * (EA);                         \
        float zB = softplusf_(sB0 + sB1) * (EB);                         \
        if (lane < 50) { ss2[P][lane] = zA; ss2[P][52 + lane] = zB; }    \
        {   /* prefetch eps(T+2): waited on 2 steps from now */          \
            int tp_ = (T) + 2 < T_LEN ? (T) + 2 : (T);                   \
            const float* ep_ = erow + (int64_t)tp_ * 100;                \
            (EA) = ep_[ls]; (EB) = ep_[ls + 50];                         \
        }                                                                \
        __builtin_amdgcn_wave_barrier();                                 \
        {                                                                \
            const float4* sp4_ = (const float4*)(&ss2[P][52 * h]);       \
            float p0 = 0.f, p1 = 0.f, p2 = 0.f, p3 = 0.f;                \
            _Pragma("unroll")                                            \
            for (int c_ = 0; c_ < 13; ++c_) {                            \
                float4 v_ = sp4_[c_];                                    \
                p0 = fmaf(wbig[4*c_+0], v_.x, p0);                       \
                p1 = fmaf(wbig[4*c_+1], v_.y, p1);                       \
                p2 = fmaf(wbig[4*c_+2], v_.z, p2);                       \
                p3 = fmaf(wbig[4*c_+3], v_.w, p3);                       \
            }                                                            \
            float p_ = (p0 + p1) + (p2 + p3);                            \
            float gi1v = p_ + __shfl_xor(p_, 32) + br1 + gq;             \
            float av   = gi1v + gh1v;                                    \
            float a10  = __shfl(av,   lane + 10);                        \
            float gin  = __shfl(gi1v, lane + 20);                        \
            float ghn  = __shfl(gh1v, lane + 20);                        \
            if (lane < 10) {                                             \
                float r_ = sigmoidf_(av);                                \
                float u_ = sigmoidf_(a10);                               \
                float n_ = tanhf_(fmaf(r_, ghn, gin));                   \
                h1keep = fmaf(u_, h1keep - n_, n_);                      \
                out[rowbase + (int64_t)(T) * 100 + 30 + lane] = h1keep;  \
            }                                                            \
        }                                                                \
        _Pragma("unroll")                                                \
        for (int k_ = 0; k_ < 10; ++k_) sh1_[k_] = bcast_(h1keep, k_);   \
    } while (0)

#define H2_STEP(T, GC)                                                   \
    do {                                                                 \
        if (lane < 10)  /* PRE-update h2 == h2_shift[T] */               \
            out[rowbase + (int64_t)(T) * 100 + 40 + lane] = h2keep;      \
        float ga = bhh2r, gb = 0.f;                                      \
        _Pragma("unroll")                                                \
        for (int k_ = 0; k_ < 5; ++k_) {                                 \
            ga = fmaf(whh2r[2*k_],   g2c[2*k_],   ga);                   \
            gb = fmaf(whh2r[2*k_+1], g2c[2*k_+1], gb);                   \
        }                                                                \
        float gh2v = ga + gb;                                            \
        float gi2v = (GC);                                               \
        {   /* prefetch gi2(T+2) */                                      \
            int tp_ = (T) + 2 < T_LEN ? (T) + 2 : (T);                   \
            (GC) = out[rowbase + (int64_t)tp_ * 100 + l30];              \
        }                                                                \
        float a2  = gi2v + gh2v;                                         \
        float a10 = __shfl(a2,   lane + 10);                             \
        float gin = __shfl(gi2v, lane + 20);                             \
        float ghn = __shfl(gh2v, lane + 20);                             \
        if (lane < 10) {                                                 \
            float r_ = sigmoidf_(a2);                                    \
            float u_ = sigmoidf_(a10);                                   \
            float n_ = tanhf_(fmaf(r_, ghn, gin));                       \
            h2keep = fmaf(u_, h2keep - n_, n_);                          \
        }                                                                \
        _Pragma("unroll")                                                \
        for (int k_ = 0; k_ < 10; ++k_) g2c[k_] = bcast_(h2keep, k_);    \
    } while (0)

__global__ __launch_bounds__(128) void scan_kernel(
    const float* __restrict__ eps,
    const float* __restrict__ W_ih1, const float* __restrict__ W_hh1,
    const float* __restrict__ b_ih1, const float* __restrict__ b_hh1,
    const float* __restrict__ W_hh2, const float* __restrict__ b_hh2,
    const float* __restrict__ h1_0,  const float* __restrict__ h2_0,
    const float* __restrict__ Wt1,   const float* __restrict__ bt1,
    const float* __restrict__ Wloc,  const float* __restrict__ bloc,
    const float* __restrict__ Wsc,   const float* __restrict__ bsc,
    float* out)
{
    __shared__ __align__(16) float ss2[2][104];      // z-tilde, parity double-buffer (wave0 only)

    const int lane = threadIdx.x & 63;
    const int64_t rowbase = (int64_t)blockIdx.x * T_LEN * 100;
    const int wave = __builtin_amdgcn_readfirstlane((int)(threadIdx.x >> 6));

    if (wave == 0) {
        // ================= wave0: h1 chain (free-running) =================
        const int j  = lane & 31;
        const int jc = j < 30 ? j : 29;
        const int h  = lane >> 5;
        const int lt = lane < 20 ? lane : 19;
        const int ls = lane < 50 ? lane : 49;

        float wt1r[10], whh1r[10], wscA[20], wscB[20], wbig[52], Cr[20];
#pragma unroll
        for (int k = 0; k < 10; ++k) {
            wt1r[k]  = Wt1[lt * 10 + k];
            whh1r[k] = W_hh1[jc * 10 + k];
        }
        float bt1r  = bt1[lt];
        float bhh1r = b_hh1[jc];
        float br1   = b_ih1[jc];
#pragma unroll
        for (int l = 0; l < 20; ++l) {
            wscA[l] = Wsc[ls * 20 + l];
            wscB[l] = Wsc[(ls + 50) * 20 + l];
        }
        float bscA = bsc[ls], bscB = bsc[ls + 50];
#pragma unroll
        for (int i = 0; i < 50; ++i) wbig[i] = W_ih1[jc * 100 + h * 50 + i];
        wbig[50] = 0.f; wbig[51] = 0.f;

        // one-off fold: Cr[l] = (W_ih1 @ Wloc)[jc][l],  dr = (W_ih1 @ bloc)[jc]
        float dr = 0.f;
#pragma unroll
        for (int l = 0; l < 20; ++l) Cr[l] = 0.f;
        for (int kk = 0; kk < 100; ++kk) {
            float w = W_ih1[jc * 100 + kk];
            dr = fmaf(w, bloc[kk], dr);
#pragma unroll
            for (int l = 0; l < 20; ++l) Cr[l] = fmaf(w, Wloc[kk * 20 + l], Cr[l]);
        }

        if (lane < 2) {
            ss2[0][50 + lane] = 0.f; ss2[0][102 + lane] = 0.f;
            ss2[1][50 + lane] = 0.f; ss2[1][102 + lane] = 0.f;
        }

        float h1keep = h1_0[lane < 10 ? lane : 0];
        float sh1_[10];
#pragma unroll
        for (int k = 0; k < 10; ++k) sh1_[k] = h1_0[k];

        const float* erow = eps + rowbase;
        float eA0 = erow[ls],        eB0 = erow[ls + 50];        // step t (even)
        float eA1 = erow[100 + ls],  eB1 = erow[100 + ls + 50];  // step t+1 (odd)

#pragma unroll 1
        for (int t = 0; t < T_LEN; t += 2) {
            H1_STEP(t,     eA0, eB0, 0);
            H1_STEP(t + 1, eA1, eB1, 1);
        }
    } else {
        // ================= wave1: h2 chain (free-running) =================
        const int l30 = lane < 30 ? lane : 29;

        float whh2r[10];
#pragma unroll
        for (int k = 0; k < 10; ++k) whh2r[k] = W_hh2[l30 * 10 + k];
        float bhh2r = b_hh2[l30];

        float h2keep = h2_0[lane < 10 ? lane : 0];
        float g2c[10];
#pragma unroll
        for (int k = 0; k < 10; ++k) g2c[k] = h2_0[k];

        float gU = out[rowbase + l30];                 // gi2(0)
        float gV = out[rowbase + 100 + l30];           // gi2(1)

#pragma unroll 1
        for (int t = 0; t < T_LEN; t += 2) {
            H2_STEP(t,     gU);
            H2_STEP(t + 1, gV);
        }
    }
}

// ---------------- K3: emitter for all (b,t) rows, massively parallel ------------------------
// Row r is self-contained: reads out[r,30:50] = [h1[t]; h2_shift[t]], writes out[r,0:100].
// 4 waves/block, 8 rows/wave (1000 = 125*8 -> a wave never crosses a batch boundary).
__global__ __launch_bounds__(256) void emit_kernel(
    const float* __restrict__ We1, const float* __restrict__ be1,
    const float* __restrict__ We2, const float* __restrict__ be2,
    const float* __restrict__ We3, const float* __restrict__ be3,
    float* out)
{
    const int lane = threadIdx.x & 63;
    const int wid  = threadIdx.x >> 6;
    const int lt = lane < 20 ? lane : 19;
    const int ls = lane < 50 ? lane : 49;

    float we1r[20], we2r[20], we3A[20], we3B[20];
#pragma unroll
    for (int k = 0; k < 20; ++k) {
        we1r[k] = We1[lt * 20 + k];
        we2r[k] = We2[lt * 20 + k];
        we3A[k] = We3[ls * 20 + k];
        we3B[k] = We3[(ls + 50) * 20 + k];
    }
    float be1r = be1[lt], be2r = be2[lt];
    float be3A = be3[ls], be3B = be3[ls + 50];

    const int64_t row0 = ((int64_t)blockIdx.x * 4 + wid) * 8;

#pragma unroll 1
    for (int rr = 0; rr < 8; ++rr) {
        const int64_t r = row0 + rr;
        float hvin = 0.f;
        if (lane < 20) hvin = out[r * 100 + 30 + lane];   // [h1[t](10); h2_shift[t](10)]

        float hall[20];
#pragma unroll
        for (int l = 0; l < 20; ++l) hall[l] = bcast_(hvin, l);

        float ea = be1r, eb = 0.f;
#pragma unroll
        for (int k = 0; k < 10; ++k) {
            ea = fmaf(we1r[2 * k],     hall[2 * k],     ea);
            eb = fmaf(we1r[2 * k + 1], hall[2 * k + 1], eb);
        }
        float e1v = fmaxf(ea + eb, 0.f);

        float se1[20];
#pragma unroll
        for (int l = 0; l < 20; ++l) se1[l] = bcast_(e1v, l);

        float fa = be2r, fb = 0.f;
#pragma unroll
        for (int k = 0; k < 10; ++k) {
            fa = fmaf(we2r[2 * k],     se1[2 * k],     fa);
            fb = fmaf(we2r[2 * k + 1], se1[2 * k + 1], fb);
        }
        float e2v = fmaxf(fa + fb, 0.f);

        float se2[20];
#pragma unroll
        for (int l = 0; l < 20; ++l) se2[l] = bcast_(e2v, l);

        float xa0 = be3A, xa1 = 0.f, xb0 = be3B, xb1 = 0.f;
#pragma unroll
        for (int l = 0; l < 10; ++l) {
            xa0 = fmaf(we3A[2 * l],     se2[2 * l],     xa0);
            xa1 = fmaf(we3A[2 * l + 1], se2[2 * l + 1], xa1);
            xb0 = fmaf(we3B[2 * l],     se2[2 * l],     xb0);
            xb1 = fmaf(we3B[2 * l + 1], se2[2 * l + 1], xb1);
        }
        float xA = sigmoidf_(xa0 + xa1);
        float xB = sigmoidf_(xb0 + xb1);
        if (lane < 50) {
            out[r * 100 + lane]      = xA;
            out[r * 100 + lane + 50] = xB;
        }
    }
}

extern "C" void kernel_launch(void* const* d_in, const int* in_sizes, int n_in,
                              void* d_out, int out_size, void* d_ws, size_t ws_size,
                              hipStream_t stream) {
    const float* mini_batch = (const float*)d_in[0];
    const float* eps        = (const float*)d_in[1];
    const float* W_ih1      = (const float*)d_in[2];
    const float* W_hh1      = (const float*)d_in[3];
    const float* b_ih1      = (const float*)d_in[4];
    const float* b_hh1      = (const float*)d_in[5];
    const float* W_ih2      = (const float*)d_in[6];
    const float* W_hh2      = (const float*)d_in[7];
    const float* b_ih2      = (const float*)d_in[8];
    const float* b_hh2      = (const float*)d_in[9];
    const float* h1_0       = (const float*)d_in[10];
    const float* h2_0       = (const float*)d_in[11];
    const float* Wt1        = (const float*)d_in[12];
    const float* bt1        = (const float*)d_in[13];
    const float* Wloc       = (const float*)d_in[14];
    const float* bloc       = (const float*)d_in[15];
    const float* Wsc        = (const float*)d_in[16];
    const float* bsc        = (const float*)d_in[17];
    const float* We1        = (const float*)d_in[18];
    const float* be1        = (const float*)d_in[19];
    const float* We2        = (const float*)d_in[20];
    const float* be2        = (const float*)d_in[21];
    const float* We3        = (const float*)d_in[22];
    const float* be3        = (const float*)d_in[23];
    float* out = (float*)d_out;

    // K1: gi2 precompute into out[.., 0:30] (scratch, overwritten by K3)
    gi2_kernel<<<(NB * T_LEN) / 64, 256, 0, stream>>>(mini_batch, W_ih2, b_ih2, out);

    // K2: two independent free-running scans per batch element (no barriers)
    scan_kernel<<<NB, 128, 0, stream>>>(eps, W_ih1, W_hh1, b_ih1, b_hh1, W_hh2, b_hh2,
                                        h1_0, h2_0, Wt1, bt1, Wloc, bloc, Wsc, bsc, out);

    // K3: emitter for all rows (reads out[r,30:50], overwrites out[r,0:100])
    emit_kernel<<<(NB * T_LEN) / 32, 256, 0, stream>>>(We1, be1, We2, be2, We3, be3, out);
}

// Round 8
// 830.595 us; speedup vs baseline: 1.1419x; 1.0026x over previous
//
#include <hip/hip_runtime.h>
#include <cstdint>

#define T_LEN 1000
#define NB    256

__device__ __forceinline__ float rcpf_(float x)     { return __builtin_amdgcn_rcpf(x); }
__device__ __forceinline__ float sigmoidf_(float x) { return rcpf_(1.f + __expf(-x)); }
__device__ __forceinline__ float tanhf_(float x) {
    float e = __expf(2.f * x);
    return 1.f - 2.f * rcpf_(e + 1.f);
}
__device__ __forceinline__ float softplusf_(float x) {
    return fmaxf(x, 0.f) + __logf(1.f + __expf(-fabsf(x)));
}
__device__ __forceinline__ float bcast_(float v, int l) {
    return __uint_as_float(__builtin_amdgcn_readlane(__float_as_uint(v), l));
}
// p_lo + p_hi for each lane pair (i, i+32) via gfx950 v_permlane32_swap (VALU-speed,
// replaces the ~120cy ds_bpermute shfl_xor). s_nops guard producer/consumer hazards.
__device__ __forceinline__ float halfsum_(float p) {
    float a = p, b = p;
    asm volatile("s_nop 1\n\tv_permlane32_swap_b32 %0, %1\n\ts_nop 1"
                 : "+v"(a), "+v"(b));
    return a + b;   // lane i<32: p[i+32]+p[i]; lane i>=32: p[i]+p[i-32]
}

// ---------------- K1: gi2 = mini_batch @ W_ih2^T + b_ih2  -> out[b,t,0:30] (scratch) --------
__global__ __launch_bounds__(256) void gi2_kernel(
    const float* __restrict__ x, const float* __restrict__ W,
    const float* __restrict__ bias, float* __restrict__ out)
{
    __shared__ float xsT[100 * 67];          // xsT[k*67 + r], 26.8 KB

    const int tid = threadIdx.x;
    const int64_t base = (int64_t)blockIdx.x * (64 * 100);
    const float4* gx = (const float4*)(x + base);

#pragma unroll
    for (int it = 0; it < 7; ++it) {
        int i = tid + it * 256;
        if (i < 1600) {
            int r  = i / 25;
            int k4 = i - r * 25;
            float4 v = gx[i];                 // coalesced 16B/lane
            xsT[(4 * k4 + 0) * 67 + r] = v.x;
            xsT[(4 * k4 + 1) * 67 + r] = v.y;
            xsT[(4 * k4 + 2) * 67 + r] = v.z;
            xsT[(4 * k4 + 3) * 67 + r] = v.w;
        }
    }
    __syncthreads();

    const int lane = tid & 63;                               // row within tile
    const int wv   = __builtin_amdgcn_readfirstlane(tid >> 6);
    const int j0   = wv * 8;                                 // 8 output cols per wave

    float acc[8];
#pragma unroll
    for (int jj = 0; jj < 8; ++jj) acc[jj] = 0.f;

    for (int k = 0; k < 100; ++k) {
        float xv = xsT[k * 67 + lane];
#pragma unroll
        for (int jj = 0; jj < 8; ++jj) {
            int j = j0 + jj; j = j > 29 ? 29 : j;            // wave-uniform -> s_load
            acc[jj] = fmaf(xv, W[j * 100 + k], acc[jj]);
        }
    }
    float* orow = out + base + (int64_t)lane * 100;
#pragma unroll
    for (int jj = 0; jj < 8; ++jj) {
        int j = j0 + jj;
        if (j < 30) orow[j] = acc[jj] + bias[j];
    }
}

// ---------------- K2: sequential scans. 1 block / batch element, 2 FREE-RUNNING waves -------
// wave0: h1 chain only -> h1[t] to out[b,t,30:40].
// wave1: h2 chain only -> PRE-update h2 (=h2_shift[t]) to out[b,t,40:50].
// Chain shortening vs R7: permlane32 half-sum (not shfl_xor), sigma computed pre-gather,
// gh1 dot + eps prefetch moved into the z LDS write->read latency window, 4-acc sc/q.

#define H1_STEP(T, EA, EB, P)                                            \
    do {                                                                 \
        /* hid from uniform h1 */                                        \
        float ha = bt1r, hb = 0.f;                                       \
        _Pragma("unroll")                                                \
        for (int k_ = 0; k_ < 5; ++k_) {                                 \
            ha = fmaf(wt1r[2*k_],   sh1_[2*k_],   ha);                   \
            hb = fmaf(wt1r[2*k_+1], sh1_[2*k_+1], hb);                   \
        }                                                                \
        float hidv = fmaxf(ha + hb, 0.f);                                \
        float sgh[20];                                                   \
        _Pragma("unroll")                                                \
        for (int l_ = 0; l_ < 20; ++l_) sgh[l_] = bcast_(hidv, l_);      \
        /* sc / folded-loc dots, 4 accumulators each */                  \
        float sA0 = bscA, sA1 = 0.f, sA2 = 0.f, sA3 = 0.f;               \
        float sB0 = bscB, sB1 = 0.f, sB2 = 0.f, sB3 = 0.f;               \
        float q0 = dr, q1 = 0.f, q2 = 0.f, q3 = 0.f;                     \
        _Pragma("unroll")                                                \
        for (int l_ = 0; l_ < 5; ++l_) {                                 \
            sA0 = fmaf(wscA[4*l_],   sgh[4*l_],   sA0);                  \
            sA1 = fmaf(wscA[4*l_+1], sgh[4*l_+1], sA1);                  \
            sA2 = fmaf(wscA[4*l_+2], sgh[4*l_+2], sA2);                  \
            sA3 = fmaf(wscA[4*l_+3], sgh[4*l_+3], sA3);                  \
            sB0 = fmaf(wscB[4*l_],   sgh[4*l_],   sB0);                  \
            sB1 = fmaf(wscB[4*l_+1], sgh[4*l_+1], sB1);                  \
            sB2 = fmaf(wscB[4*l_+2], sgh[4*l_+2], sB2);                  \
            sB3 = fmaf(wscB[4*l_+3], sgh[4*l_+3], sB3);                  \
            q0  = fmaf(Cr[4*l_],     sgh[4*l_],   q0);                   \
            q1  = fmaf(Cr[4*l_+1],   sgh[4*l_+1], q1);                   \
            q2  = fmaf(Cr[4*l_+2],   sgh[4*l_+2], q2);                   \
            q3  = fmaf(Cr[4*l_+3],   sgh[4*l_+3], q3);                   \
        }                                                                \
        float gq = (q0 + q1) + (q2 + q3);                                \
        float zA = softplusf_((sA0 + sA1) + (sA2 + sA3)) * (EA);         \
        float zB = softplusf_((sB0 + sB1) + (sB2 + sB3)) * (EB);         \
        if (lane < 50) { ss2[P][lane] = zA; ss2[P][52 + lane] = zB; }    \
        /* shadow of LDS write->read latency: gh1 dot + eps prefetch */  \
        float ga = bhh1r, gb = 0.f;                                      \
        _Pragma("unroll")                                                \
        for (int k_ = 0; k_ < 5; ++k_) {                                 \
            ga = fmaf(whh1r[2*k_],   sh1_[2*k_],   ga);                  \
            gb = fmaf(whh1r[2*k_+1], sh1_[2*k_+1], gb);                  \
        }                                                                \
        float gh1v = ga + gb;                                            \
        {                                                                \
            int tp_ = (T) + 2 < T_LEN ? (T) + 2 : (T);                   \
            const float* ep_ = erow + (int64_t)tp_ * 100;                \
            (EA) = ep_[ls]; (EB) = ep_[ls + 50];                         \
        }                                                                \
        /* gi1 partial dot over own k-half (LDS in-order same-wave) */   \
        {                                                                \
            const float4* sp4_ = (const float4*)(&ss2[P][52 * h]);       \
            float p0 = 0.f, p1 = 0.f, p2 = 0.f, p3 = 0.f;                \
            _Pragma("unroll")                                            \
            for (int c_ = 0; c_ < 13; ++c_) {                            \
                float4 v_ = sp4_[c_];                                    \
                p0 = fmaf(wbig[4*c_+0], v_.x, p0);                       \
                p1 = fmaf(wbig[4*c_+1], v_.y, p1);                       \
                p2 = fmaf(wbig[4*c_+2], v_.z, p2);                       \
                p3 = fmaf(wbig[4*c_+3], v_.w, p3);                       \
            }                                                            \
            float p_ = (p0 + p1) + (p2 + p3);                            \
            float gi1v = halfsum_(p_) + br1 + gq;                        \
            float av   = gi1v + gh1v;                                    \
            float sg   = sigmoidf_(av);       /* sigma in ALL lanes */   \
            float su   = __shfl(sg,   lane + 10);                        \
            float gin  = __shfl(gi1v, lane + 20);                        \
            float ghn  = __shfl(gh1v, lane + 20);                        \
            if (lane < 10) {                                             \
                float n_ = tanhf_(fmaf(sg, ghn, gin));                   \
                h1keep = fmaf(su, h1keep - n_, n_);                      \
                out[rowbase + (int64_t)(T) * 100 + 30 + lane] = h1keep;  \
            }                                                            \
        }                                                                \
        _Pragma("unroll")                                                \
        for (int k_ = 0; k_ < 10; ++k_) sh1_[k_] = bcast_(h1keep, k_);   \
    } while (0)

#define H2_STEP(T, GC)                                                   \
    do {                                                                 \
        if (lane < 10)  /* PRE-update h2 == h2_shift[T] */               \
            out[rowbase + (int64_t)(T) * 100 + 40 + lane] = h2keep;      \
        float ga = bhh2r, gb = 0.f;                                      \
        _Pragma("unroll")                                                \
        for (int k_ = 0; k_ < 5; ++k_) {                                 \
            ga = fmaf(whh2r[2*k_],   g2c[2*k_],   ga);                   \
            gb = fmaf(whh2r[2*k_+1], g2c[2*k_+1], gb);                   \
        }                                                                \
        float gh2v = ga + gb;                                            \
        float gi2v = (GC);                                               \
        {   /* prefetch gi2(T+2) */                                      \
            int tp_ = (T) + 2 < T_LEN ? (T) + 2 : (T);                   \
            (GC) = out[rowbase + (int64_t)tp_ * 100 + l30];              \
        }                                                                \
        float a2  = gi2v + gh2v;                                         \
        float sg2 = sigmoidf_(a2);            /* sigma in ALL lanes */   \
        float su  = __shfl(sg2,  lane + 10);                             \
        float gin = __shfl(gi2v, lane + 20);                             \
        float ghn = __shfl(gh2v, lane + 20);                             \
        if (lane < 10) {                                                 \
            float n_ = tanhf_(fmaf(sg2, ghn, gin));                      \
            h2keep = fmaf(su, h2keep - n_, n_);                          \
        }                                                                \
        _Pragma("unroll")                                                \
        for (int k_ = 0; k_ < 10; ++k_) g2c[k_] = bcast_(h2keep, k_);    \
    } while (0)

__global__ __launch_bounds__(128) void scan_kernel(
    const float* __restrict__ eps,
    const float* __restrict__ W_ih1, const float* __restrict__ W_hh1,
    const float* __restrict__ b_ih1, const float* __restrict__ b_hh1,
    const float* __restrict__ W_hh2, const float* __restrict__ b_hh2,
    const float* __restrict__ h1_0,  const float* __restrict__ h2_0,
    const float* __restrict__ Wt1,   const float* __restrict__ bt1,
    const float* __restrict__ Wloc,  const float* __restrict__ bloc,
    const float* __restrict__ Wsc,   const float* __restrict__ bsc,
    float* out)
{
    __shared__ __align__(16) float ss2[2][104];      // z-tilde, parity double-buffer (wave0 only)

    const int lane = threadIdx.x & 63;
    const int64_t rowbase = (int64_t)blockIdx.x * T_LEN * 100;
    const int wave = __builtin_amdgcn_readfirstlane((int)(threadIdx.x >> 6));

    if (wave == 0) {
        // ================= wave0: h1 chain (free-running) =================
        const int j  = lane & 31;
        const int jc = j < 30 ? j : 29;
        const int h  = lane >> 5;
        const int lt = lane < 20 ? lane : 19;
        const int ls = lane < 50 ? lane : 49;

        float wt1r[10], whh1r[10], wscA[20], wscB[20], wbig[52], Cr[20];
#pragma unroll
        for (int k = 0; k < 10; ++k) {
            wt1r[k]  = Wt1[lt * 10 + k];
            whh1r[k] = W_hh1[jc * 10 + k];
        }
        float bt1r  = bt1[lt];
        float bhh1r = b_hh1[jc];
        float br1   = b_ih1[jc];
#pragma unroll
        for (int l = 0; l < 20; ++l) {
            wscA[l] = Wsc[ls * 20 + l];
            wscB[l] = Wsc[(ls + 50) * 20 + l];
        }
        float bscA = bsc[ls], bscB = bsc[ls + 50];
#pragma unroll
        for (int i = 0; i < 50; ++i) wbig[i] = W_ih1[jc * 100 + h * 50 + i];
        wbig[50] = 0.f; wbig[51] = 0.f;

        // one-off fold: Cr[l] = (W_ih1 @ Wloc)[jc][l],  dr = (W_ih1 @ bloc)[jc]
        float dr = 0.f;
#pragma unroll
        for (int l = 0; l < 20; ++l) Cr[l] = 0.f;
        for (int kk = 0; kk < 100; ++kk) {
            float w = W_ih1[jc * 100 + kk];
            dr = fmaf(w, bloc[kk], dr);
#pragma unroll
            for (int l = 0; l < 20; ++l) Cr[l] = fmaf(w, Wloc[kk * 20 + l], Cr[l]);
        }

        if (lane < 2) {
            ss2[0][50 + lane] = 0.f; ss2[0][102 + lane] = 0.f;
            ss2[1][50 + lane] = 0.f; ss2[1][102 + lane] = 0.f;
        }

        float h1keep = h1_0[lane < 10 ? lane : 0];
        float sh1_[10];
#pragma unroll
        for (int k = 0; k < 10; ++k) sh1_[k] = h1_0[k];

        const float* erow = eps + rowbase;
        float eA0 = erow[ls],        eB0 = erow[ls + 50];        // step t (even)
        float eA1 = erow[100 + ls],  eB1 = erow[100 + ls + 50];  // step t+1 (odd)

#pragma unroll 1
        for (int t = 0; t < T_LEN; t += 2) {
            H1_STEP(t,     eA0, eB0, 0);
            H1_STEP(t + 1, eA1, eB1, 1);
        }
    } else {
        // ================= wave1: h2 chain (free-running) =================
        const int l30 = lane < 30 ? lane : 29;

        float whh2r[10];
#pragma unroll
        for (int k = 0; k < 10; ++k) whh2r[k] = W_hh2[l30 * 10 + k];
        float bhh2r = b_hh2[l30];

        float h2keep = h2_0[lane < 10 ? lane : 0];
        float g2c[10];
#pragma unroll
        for (int k = 0; k < 10; ++k) g2c[k] = h2_0[k];

        float gU = out[rowbase + l30];                 // gi2(0)
        float gV = out[rowbase + 100 + l30];           // gi2(1)

#pragma unroll 1
        for (int t = 0; t < T_LEN; t += 2) {
            H2_STEP(t,     gU);
            H2_STEP(t + 1, gV);
        }
    }
}

// ---------------- K3: emitter for all (b,t) rows, massively parallel ------------------------
// Row r is self-contained: reads out[r,30:50] = [h1[t]; h2_shift[t]], writes out[r,0:100].
// unroll 2: two independent rows interleave -> readlane/broadcast latency overlapped.
__global__ __launch_bounds__(256) void emit_kernel(
    const float* __restrict__ We1, const float* __restrict__ be1,
    const float* __restrict__ We2, const float* __restrict__ be2,
    const float* __restrict__ We3, const float* __restrict__ be3,
    float* out)
{
    const int lane = threadIdx.x & 63;
    const int wid  = threadIdx.x >> 6;
    const int lt = lane < 20 ? lane : 19;
    const int ls = lane < 50 ? lane : 49;

    float we1r[20], we2r[20], we3A[20], we3B[20];
#pragma unroll
    for (int k = 0; k < 20; ++k) {
        we1r[k] = We1[lt * 20 + k];
        we2r[k] = We2[lt * 20 + k];
        we3A[k] = We3[ls * 20 + k];
        we3B[k] = We3[(ls + 50) * 20 + k];
    }
    float be1r = be1[lt], be2r = be2[lt];
    float be3A = be3[ls], be3B = be3[ls + 50];

    const int64_t row0 = ((int64_t)blockIdx.x * 4 + wid) * 8;

#pragma unroll 2
    for (int rr = 0; rr < 8; ++rr) {
        const int64_t r = row0 + rr;
        float hvin = 0.f;
        if (lane < 20) hvin = out[r * 100 + 30 + lane];   // [h1[t](10); h2_shift[t](10)]

        float hall[20];
#pragma unroll
        for (int l = 0; l < 20; ++l) hall[l] = bcast_(hvin, l);

        float ea = be1r, eb = 0.f;
#pragma unroll
        for (int k = 0; k < 10; ++k) {
            ea = fmaf(we1r[2 * k],     hall[2 * k],     ea);
            eb = fmaf(we1r[2 * k + 1], hall[2 * k + 1], eb);
        }
        float e1v = fmaxf(ea + eb, 0.f);

        float se1[20];
#pragma unroll
        for (int l = 0; l < 20; ++l) se1[l] = bcast_(e1v, l);

        float fa = be2r, fb = 0.f;
#pragma unroll
        for (int k = 0; k < 10; ++k) {
            fa = fmaf(we2r[2 * k],     se1[2 * k],     fa);
            fb = fmaf(we2r[2 * k + 1], se1[2 * k + 1], fb);
        }
        float e2v = fmaxf(fa + fb, 0.f);

        float se2[20];
#pragma unroll
        for (int l = 0; l < 20; ++l) se2[l] = bcast_(e2v, l);

        float xa0 = be3A, xa1 = 0.f, xb0 = be3B, xb1 = 0.f;
#pragma unroll
        for (int l = 0; l < 10; ++l) {
            xa0 = fmaf(we3A[2 * l],     se2[2 * l],     xa0);
            xa1 = fmaf(we3A[2 * l + 1], se2[2 * l + 1], xa1);
            xb0 = fmaf(we3B[2 * l],     se2[2 * l],     xb0);
            xb1 = fmaf(we3B[2 * l + 1], se2[2 * l + 1], xb1);
        }
        float xA = sigmoidf_(xa0 + xa1);
        float xB = sigmoidf_(xb0 + xb1);
        if (lane < 50) {
            out[r * 100 + lane]      = xA;
            out[r * 100 + lane + 50] = xB;
        }
    }
}

extern "C" void kernel_launch(void* const* d_in, const int* in_sizes, int n_in,
                              void* d_out, int out_size, void* d_ws, size_t ws_size,
                              hipStream_t stream) {
    const float* mini_batch = (const float*)d_in[0];
    const float* eps        = (const float*)d_in[1];
    const float* W_ih1      = (const float*)d_in[2];
    const float* W_hh1      = (const float*)d_in[3];
    const float* b_ih1      = (const float*)d_in[4];
    const float* b_hh1      = (const float*)d_in[5];
    const float* W_ih2      = (const float*)d_in[6];
    const float* W_hh2      = (const float*)d_in[7];
    const float* b_ih2      = (const float*)d_in[8];
    const float* b_hh2      = (const float*)d_in[9];
    const float* h1_0       = (const float*)d_in[10];
    const float* h2_0       = (const float*)d_in[11];
    const float* Wt1        = (const float*)d_in[12];
    const float* bt1        = (const float*)d_in[13];
    const float* Wloc       = (const float*)d_in[14];
    const float* bloc       = (const float*)d_in[15];
    const float* Wsc        = (const float*)d_in[16];
    const float* bsc        = (const float*)d_in[17];
    const float* We1        = (const float*)d_in[18];
    const float* be1        = (const float*)d_in[19];
    const float* We2        = (const float*)d_in[20];
    const float* be2        = (const float*)d_in[21];
    const float* We3        = (const float*)d_in[22];
    const float* be3        = (const float*)d_in[23];
    float* out = (float*)d_out;

    // K1: gi2 precompute into out[.., 0:30] (scratch, overwritten by K3)
    gi2_kernel<<<(NB * T_LEN) / 64, 256, 0, stream>>>(mini_batch, W_ih2, b_ih2, out);

    // K2: two independent free-running scans per batch element (no barriers)
    scan_kernel<<<NB, 128, 0, stream>>>(eps, W_ih1, W_hh1, b_ih1, b_hh1, W_hh2, b_hh2,
                                        h1_0, h2_0, Wt1, bt1, Wloc, bloc, Wsc, bsc, out);

    // K3: emitter for all rows (reads out[r,30:50], overwrites out[r,0:100])
    emit_kernel<<<(NB * T_LEN) / 32, 256, 0, stream>>>(We1, be1, We2, be2, We3, be3, out);
}

// Round 9
// 802.406 us; speedup vs baseline: 1.1821x; 1.0351x over previous
//
#include <hip/hip_runtime.h>
#include <cstdint>

#define T_LEN 1000
#define NB    256

__device__ __forceinline__ float rcpf_(float x)     { return __builtin_amdgcn_rcpf(x); }
__device__ __forceinline__ float sigmoidf_(float x) { return rcpf_(1.f + __expf(-x)); }
__device__ __forceinline__ float tanhf_(float x) {
    float e = __expf(2.f * x);
    return 1.f - 2.f * rcpf_(e + 1.f);
}
__device__ __forceinline__ float softplusf_(float x) {
    return fmaxf(x, 0.f) + __logf(1.f + __expf(-fabsf(x)));
}
__device__ __forceinline__ float bcast_(float v, int l) {
    return __uint_as_float(__builtin_amdgcn_readlane(__float_as_uint(v), l));
}
// p_lo + p_hi for each lane pair (i, i+32) via gfx950 v_permlane32_swap (VALU-speed).
__device__ __forceinline__ float halfsum_(float p) {
    float a = p, b = p;
    asm volatile("s_nop 1\n\tv_permlane32_swap_b32 %0, %1\n\ts_nop 1"
                 : "+v"(a), "+v"(b));
    return a + b;
}

// ---------------- K1: gi2 = mini_batch @ W_ih2^T + b_ih2  -> out[b,t,0:30] (scratch) --------
__global__ __launch_bounds__(256) void gi2_kernel(
    const float* __restrict__ x, const float* __restrict__ W,
    const float* __restrict__ bias, float* __restrict__ out)
{
    __shared__ float xsT[100 * 67];          // xsT[k*67 + r], 26.8 KB

    const int tid = threadIdx.x;
    const int64_t base = (int64_t)blockIdx.x * (64 * 100);
    const float4* gx = (const float4*)(x + base);

#pragma unroll
    for (int it = 0; it < 7; ++it) {
        int i = tid + it * 256;
        if (i < 1600) {
            int r  = i / 25;
            int k4 = i - r * 25;
            float4 v = gx[i];                 // coalesced 16B/lane
            xsT[(4 * k4 + 0) * 67 + r] = v.x;
            xsT[(4 * k4 + 1) * 67 + r] = v.y;
            xsT[(4 * k4 + 2) * 67 + r] = v.z;
            xsT[(4 * k4 + 3) * 67 + r] = v.w;
        }
    }
    __syncthreads();

    const int lane = tid & 63;                               // row within tile
    const int wv   = __builtin_amdgcn_readfirstlane(tid >> 6);
    const int j0   = wv * 8;                                 // 8 output cols per wave

    float acc[8];
#pragma unroll
    for (int jj = 0; jj < 8; ++jj) acc[jj] = 0.f;

    for (int k = 0; k < 100; ++k) {
        float xv = xsT[k * 67 + lane];
#pragma unroll
        for (int jj = 0; jj < 8; ++jj) {
            int j = j0 + jj; j = j > 29 ? 29 : j;            // wave-uniform -> s_load
            acc[jj] = fmaf(xv, W[j * 100 + k], acc[jj]);
        }
    }
    float* orow = out + base + (int64_t)lane * 100;
#pragma unroll
    for (int jj = 0; jj < 8; ++jj) {
        int j = j0 + jj;
        if (j < 30) orow[j] = acc[jj] + bias[j];
    }
}

// ---------------- K2: sequential scan. 1 block / batch element, 2 waves ---------------------
// Consolidated best-measured structure (R2) + verified micro-opts (R8):
// wave0: h1 critical chain (permlane32 halfsum, sigma-pre-gather, 4-acc dots, gh1+eps
//        prefetch in the z LDS-write shadow). Publishes h1(t) to sh1ring.
// wave1: h2 GRU + full emitter (lagged 1 step) + final output stores. No separate K3 pass.

#define H1_STEP(T, EA, EB)                                               \
    do {                                                                 \
        /* hid from uniform h1 */                                        \
        float ha = bt1r, hb = 0.f;                                       \
        _Pragma("unroll")                                                \
        for (int k_ = 0; k_ < 5; ++k_) {                                 \
            ha = fmaf(wt1r[2*k_],   sh1_[2*k_],   ha);                   \
            hb = fmaf(wt1r[2*k_+1], sh1_[2*k_+1], hb);                   \
        }                                                                \
        float hidv = fmaxf(ha + hb, 0.f);                                \
        float sgh[20];                                                   \
        _Pragma("unroll")                                                \
        for (int l_ = 0; l_ < 20; ++l_) sgh[l_] = bcast_(hidv, l_);      \
        /* sc / folded-loc dots, 4 accumulators each */                  \
        float sA0 = bscA, sA1 = 0.f, sA2 = 0.f, sA3 = 0.f;               \
        float sB0 = bscB, sB1 = 0.f, sB2 = 0.f, sB3 = 0.f;               \
        float q0 = dr, q1 = 0.f, q2 = 0.f, q3 = 0.f;                     \
        _Pragma("unroll")                                                \
        for (int l_ = 0; l_ < 5; ++l_) {                                 \
            sA0 = fmaf(wscA[4*l_],   sgh[4*l_],   sA0);                  \
            sA1 = fmaf(wscA[4*l_+1], sgh[4*l_+1], sA1);                  \
            sA2 = fmaf(wscA[4*l_+2], sgh[4*l_+2], sA2);                  \
            sA3 = fmaf(wscA[4*l_+3], sgh[4*l_+3], sA3);                  \
            sB0 = fmaf(wscB[4*l_],   sgh[4*l_],   sB0);                  \
            sB1 = fmaf(wscB[4*l_+1], sgh[4*l_+1], sB1);                  \
            sB2 = fmaf(wscB[4*l_+2], sgh[4*l_+2], sB2);                  \
            sB3 = fmaf(wscB[4*l_+3], sgh[4*l_+3], sB3);                  \
            q0  = fmaf(Cr[4*l_],     sgh[4*l_],   q0);                   \
            q1  = fmaf(Cr[4*l_+1],   sgh[4*l_+1], q1);                   \
            q2  = fmaf(Cr[4*l_+2],   sgh[4*l_+2], q2);                   \
            q3  = fmaf(Cr[4*l_+3],   sgh[4*l_+3], q3);                   \
        }                                                                \
        float gq = (q0 + q1) + (q2 + q3);                                \
        float zA = softplusf_((sA0 + sA1) + (sA2 + sA3)) * (EA);         \
        float zB = softplusf_((sB0 + sB1) + (sB2 + sB3)) * (EB);         \
        if (lane < 50) { ss2[lane] = zA; ss2[52 + lane] = zB; }          \
        /* shadow of LDS write->read latency: gh1 dot + eps prefetch */  \
        float ga = bhh1r, gb = 0.f;                                      \
        _Pragma("unroll")                                                \
        for (int k_ = 0; k_ < 5; ++k_) {                                 \
            ga = fmaf(whh1r[2*k_],   sh1_[2*k_],   ga);                  \
            gb = fmaf(whh1r[2*k_+1], sh1_[2*k_+1], gb);                  \
        }                                                                \
        float gh1v = ga + gb;                                            \
        {                                                                \
            int tp_ = (T) + 2 < T_LEN ? (T) + 2 : (T);                   \
            const float* ep_ = erow + (int64_t)tp_ * 100;                \
            (EA) = ep_[ls]; (EB) = ep_[ls + 50];                         \
        }                                                                \
        __builtin_amdgcn_wave_barrier();                                 \
        /* gi1 partial dot over own k-half (LDS in-order same-wave) */   \
        {                                                                \
            const float4* sp4_ = (const float4*)(&ss2[52 * h]);          \
            float p0 = 0.f, p1 = 0.f, p2 = 0.f, p3 = 0.f;                \
            _Pragma("unroll")                                            \
            for (int c_ = 0; c_ < 13; ++c_) {                            \
                float4 v_ = sp4_[c_];                                    \
                p0 = fmaf(wbig[4*c_+0], v_.x, p0);                       \
                p1 = fmaf(wbig[4*c_+1], v_.y, p1);                       \
                p2 = fmaf(wbig[4*c_+2], v_.z, p2);                       \
                p3 = fmaf(wbig[4*c_+3], v_.w, p3);                       \
            }                                                            \
            float p_ = (p0 + p1) + (p2 + p3);                            \
            float gi1v = halfsum_(p_) + br1 + gq;                        \
            float av   = gi1v + gh1v;                                    \
            float sg   = sigmoidf_(av);       /* sigma in ALL lanes */   \
            float su   = __shfl(sg,   lane + 10);                        \
            float gin  = __shfl(gi1v, lane + 20);                        \
            float ghn  = __shfl(gh1v, lane + 20);                        \
            if (lane < 10) {                                             \
                float n_ = tanhf_(fmaf(sg, ghn, gin));                   \
                h1keep = fmaf(su, h1keep - n_, n_);                      \
                sh1ring[(T) & 1][lane] = h1keep;    /* hand-off */       \
            }                                                            \
        }                                                                \
        _Pragma("unroll")                                                \
        for (int k_ = 0; k_ < 10; ++k_) sh1_[k_] = bcast_(h1keep, k_);   \
    } while (0)

__global__ __launch_bounds__(128) void scan_kernel(
    const float* __restrict__ eps,
    const float* __restrict__ W_ih1, const float* __restrict__ W_hh1,
    const float* __restrict__ b_ih1, const float* __restrict__ b_hh1,
    const float* __restrict__ W_hh2, const float* __restrict__ b_hh2,
    const float* __restrict__ h1_0,  const float* __restrict__ h2_0,
    const float* __restrict__ Wt1,   const float* __restrict__ bt1,
    const float* __restrict__ Wloc,  const float* __restrict__ bloc,
    const float* __restrict__ Wsc,   const float* __restrict__ bsc,
    const float* __restrict__ We1,   const float* __restrict__ be1,
    const float* __restrict__ We2,   const float* __restrict__ be2,
    const float* __restrict__ We3,   const float* __restrict__ be3,
    float* out)
{
    __shared__ __align__(16) float ss2[104];         // z-tilde, padded halves (wave0-private)
    __shared__ __align__(16) float sh1ring[2][12];   // h1 after step t -> slot t&1 (w0 -> w1)

    const int lane = threadIdx.x & 63;
    const int64_t rowbase = (int64_t)blockIdx.x * T_LEN * 100;
    const int wave = __builtin_amdgcn_readfirstlane((int)(threadIdx.x >> 6));

    if (wave == 0) {
        // ================= wave0: h1 chain =================
        const int j  = lane & 31;
        const int jc = j < 30 ? j : 29;
        const int h  = lane >> 5;
        const int lt = lane < 20 ? lane : 19;
        const int ls = lane < 50 ? lane : 49;

        float wt1r[10], whh1r[10], wscA[20], wscB[20], wbig[52], Cr[20];
#pragma unroll
        for (int k = 0; k < 10; ++k) {
            wt1r[k]  = Wt1[lt * 10 + k];
            whh1r[k] = W_hh1[jc * 10 + k];
        }
        float bt1r  = bt1[lt];
        float bhh1r = b_hh1[jc];
        float br1   = b_ih1[jc];
#pragma unroll
        for (int l = 0; l < 20; ++l) {
            wscA[l] = Wsc[ls * 20 + l];
            wscB[l] = Wsc[(ls + 50) * 20 + l];
        }
        float bscA = bsc[ls], bscB = bsc[ls + 50];
#pragma unroll
        for (int i = 0; i < 50; ++i) wbig[i] = W_ih1[jc * 100 + h * 50 + i];
        wbig[50] = 0.f; wbig[51] = 0.f;

        // one-off fold: Cr[l] = (W_ih1 @ Wloc)[jc][l],  dr = (W_ih1 @ bloc)[jc]
        float dr = 0.f;
#pragma unroll
        for (int l = 0; l < 20; ++l) Cr[l] = 0.f;
        for (int kk = 0; kk < 100; ++kk) {
            float w = W_ih1[jc * 100 + kk];
            dr = fmaf(w, bloc[kk], dr);
#pragma unroll
            for (int l = 0; l < 20; ++l) Cr[l] = fmaf(w, Wloc[kk * 20 + l], Cr[l]);
        }

        if (lane < 2) { ss2[50 + lane] = 0.f; ss2[102 + lane] = 0.f; }   // zero pads

        float h1keep = h1_0[lane < 10 ? lane : 0];
        float sh1_[10];
#pragma unroll
        for (int k = 0; k < 10; ++k) sh1_[k] = h1_0[k];

        const float* erow = eps + rowbase;
        float eA0 = erow[ls],        eB0 = erow[ls + 50];        // step t (even)
        float eA1 = erow[100 + ls],  eB1 = erow[100 + ls + 50];  // step t+1 (odd)

#pragma unroll 1
        for (int t = 0; t < T_LEN; t += 2) {
            H1_STEP(t, eA0, eB0);
            __syncthreads();
            H1_STEP(t + 1, eA1, eB1);
            __syncthreads();
        }
        __syncthreads();   // match wave1's final (t == T_LEN) iteration
    } else {
        // ================= wave1: h2 chain + emitter(t-1) + stores =================
        const int lt20 = lane < 20 ? lane : 19;
        const int l30  = lane < 30 ? lane : 29;
        const int ls   = lane < 50 ? lane : 49;

        float whh2r[10];
#pragma unroll
        for (int k = 0; k < 10; ++k) whh2r[k] = W_hh2[l30 * 10 + k];
        float bhh2r = b_hh2[l30];

        float we1r[20], we2r[20], we3A[20], we3B[20];
#pragma unroll
        for (int k = 0; k < 20; ++k) {
            we1r[k] = We1[lt20 * 20 + k];
            we2r[k] = We2[lt20 * 20 + k];
            we3A[k] = We3[ls * 20 + k];
            we3B[k] = We3[(ls + 50) * 20 + k];
        }
        float be1r = be1[lt20], be2r = be2[lt20];
        float be3A = be3[ls],   be3B = be3[ls + 50];

        float h2keep = h2_0[lane < 10 ? lane : 0];
        float g2c[10], g2p[10];                  // H2(t), H2(t-1) as broadcast scalars
#pragma unroll
        for (int k = 0; k < 10; ++k) { g2c[k] = h2_0[k]; g2p[k] = h2_0[k]; }

        float gcur = out[rowbase + l30];                 // gi2(0)
        float gnxt = out[rowbase + 100 + l30];           // gi2(1)

#pragma unroll 1
        for (int t = 0; t <= T_LEN; ++t) {
            const bool upd = (t < T_LEN);

            // early h1(t-1) read for emitter (latency hidden under h2 GRU)
            float4 d0 = make_float4(0.f, 0.f, 0.f, 0.f);
            float4 d1 = d0; float d8 = 0.f, d9 = 0.f;
            if (t >= 1) {
                const int s1 = (t - 1) & 1;
                d0 = *(const float4*)(&sh1ring[s1][0]);
                d1 = *(const float4*)(&sh1ring[s1][4]);
                d8 = sh1ring[s1][8]; d9 = sh1ring[s1][9];
            }

            if (upd) {
                float ga = bhh2r, gb = 0.f;
#pragma unroll
                for (int k = 0; k < 5; ++k) {
                    ga = fmaf(whh2r[2 * k],     g2c[2 * k],     ga);
                    gb = fmaf(whh2r[2 * k + 1], g2c[2 * k + 1], gb);
                }
                float gh2v = ga + gb;
                float gi2v = gcur;
                gcur = gnxt;
                {
                    int tp = t + 2 < T_LEN ? t + 2 : T_LEN - 1;
                    gnxt = out[rowbase + (int64_t)tp * 100 + l30];
                }
                float a2  = gi2v + gh2v;
                float sg2 = sigmoidf_(a2);        // sigma in ALL lanes
                float su  = __shfl(sg2,  lane + 10);
                float gin = __shfl(gi2v, lane + 20);
                float ghn = __shfl(gh2v, lane + 20);
                if (lane < 10) {
                    float n_ = tanhf_(fmaf(sg2, ghn, gin));
                    h2keep = fmaf(su, h2keep - n_, n_);    // H2(t+1)
                }
            }

            if (t >= 1) {
                // emitter step s = t-1: h1(s) from LDS ring, H2(s)=g2p broadcast
                float ea = be1r, eb = 0.f;
                ea = fmaf(we1r[0], d0.x, ea); eb = fmaf(we1r[1], d0.y, eb);
                ea = fmaf(we1r[2], d0.z, ea); eb = fmaf(we1r[3], d0.w, eb);
                ea = fmaf(we1r[4], d1.x, ea); eb = fmaf(we1r[5], d1.y, eb);
                ea = fmaf(we1r[6], d1.z, ea); eb = fmaf(we1r[7], d1.w, eb);
                ea = fmaf(we1r[8], d8,   ea); eb = fmaf(we1r[9], d9,   eb);
#pragma unroll
                for (int k = 0; k < 5; ++k) {
                    ea = fmaf(we1r[10 + 2 * k],     g2p[2 * k],     ea);
                    eb = fmaf(we1r[10 + 2 * k + 1], g2p[2 * k + 1], eb);
                }
                float e1v = fmaxf(ea + eb, 0.f);

                float se1v[20];
#pragma unroll
                for (int l = 0; l < 20; ++l) se1v[l] = bcast_(e1v, l);

                float fa = be2r, fb = 0.f;
#pragma unroll
                for (int k = 0; k < 10; ++k) {
                    fa = fmaf(we2r[2 * k],     se1v[2 * k],     fa);
                    fb = fmaf(we2r[2 * k + 1], se1v[2 * k + 1], fb);
                }
                float e2v = fmaxf(fa + fb, 0.f);

                float se2v[20];
#pragma unroll
                for (int l = 0; l < 20; ++l) se2v[l] = bcast_(e2v, l);

                float xa0 = be3A, xa1 = 0.f, xb0 = be3B, xb1 = 0.f;
#pragma unroll
                for (int l = 0; l < 10; ++l) {
                    xa0 = fmaf(we3A[2 * l],     se2v[2 * l],     xa0);
                    xa1 = fmaf(we3A[2 * l + 1], se2v[2 * l + 1], xa1);
                    xb0 = fmaf(we3B[2 * l],     se2v[2 * l],     xb0);
                    xb1 = fmaf(we3B[2 * l + 1], se2v[2 * l + 1], xb1);
                }
                float xA = sigmoidf_(xa0 + xa1);
                float xB = sigmoidf_(xb0 + xb1);
                if (lane < 50) {
                    int64_t ro = rowbase + (int64_t)(t - 1) * 100;
                    out[ro + lane]      = xA;        // final output, fire-and-forget
                    out[ro + lane + 50] = xB;
                }
            }

            if (upd) {
#pragma unroll
                for (int k = 0; k < 10; ++k) g2p[k] = g2c[k];
#pragma unroll
                for (int k = 0; k < 10; ++k) g2c[k] = bcast_(h2keep, k);
            }
            __syncthreads();
        }
    }
}

extern "C" void kernel_launch(void* const* d_in, const int* in_sizes, int n_in,
                              void* d_out, int out_size, void* d_ws, size_t ws_size,
                              hipStream_t stream) {
    const float* mini_batch = (const float*)d_in[0];
    const float* eps        = (const float*)d_in[1];
    const float* W_ih1      = (const float*)d_in[2];
    const float* W_hh1      = (const float*)d_in[3];
    const float* b_ih1      = (const float*)d_in[4];
    const float* b_hh1      = (const float*)d_in[5];
    const float* W_ih2      = (const float*)d_in[6];
    const float* W_hh2      = (const float*)d_in[7];
    const float* b_ih2      = (const float*)d_in[8];
    const float* b_hh2      = (const float*)d_in[9];
    const float* h1_0       = (const float*)d_in[10];
    const float* h2_0       = (const float*)d_in[11];
    const float* Wt1        = (const float*)d_in[12];
    const float* bt1        = (const float*)d_in[13];
    const float* Wloc       = (const float*)d_in[14];
    const float* bloc       = (const float*)d_in[15];
    const float* Wsc        = (const float*)d_in[16];
    const float* bsc        = (const float*)d_in[17];
    const float* We1        = (const float*)d_in[18];
    const float* be1        = (const float*)d_in[19];
    const float* We2        = (const float*)d_in[20];
    const float* be2        = (const float*)d_in[21];
    const float* We3        = (const float*)d_in[22];
    const float* be3        = (const float*)d_in[23];
    float* out = (float*)d_out;

    // K1: gi2 precompute into out[.., 0:30] (scratch, overwritten by scan's emitter)
    gi2_kernel<<<(NB * T_LEN) / 64, 256, 0, stream>>>(mini_batch, W_ih2, b_ih2, out);

    // K2: sequential scan, one block per batch element; emitter fused on wave1
    scan_kernel<<<NB, 128, 0, stream>>>(eps, W_ih1, W_hh1, b_ih1, b_hh1, W_hh2, b_hh2,
                                        h1_0, h2_0, Wt1, bt1, Wloc, bloc, Wsc, bsc,
                                        We1, be1, We2, be2, We3, be3, out);
}